// Round 10
// baseline (452.094 us; speedup 1.0000x reference)
//
#include <hip/hip_runtime.h>

#define B_ 128
#define S_ 512
#define H_ 256
#define M_ (B_*S_)

typedef __attribute__((ext_vector_type(4))) float f32x4;
typedef __attribute__((ext_vector_type(8))) short s16x8;
typedef __attribute__((ext_vector_type(4))) unsigned short u16x4;
typedef unsigned short ushort_t;

typedef __attribute__((address_space(1))) void as1_void;
typedef __attribute__((address_space(3))) void as3_void;

__device__ __forceinline__ unsigned short f2h(float f) {
  _Float16 h = (_Float16)f;              // v_cvt_f16_f32, RTNE
  return __builtin_bit_cast(unsigned short, h);
}
__device__ __forceinline__ float h2f(ushort_t u) {
  return (float)__builtin_bit_cast(_Float16, u);
}

__device__ __forceinline__ f32x4 mfma16(s16x8 a, s16x8 b, f32x4 c) {
  asm("v_mfma_f32_16x16x32_f16 %0, %1, %2, %0" : "+v"(c) : "v"(a), "v"(b));
  return c;
}

__device__ __forceinline__ void cp16(const void* g, void* l) {
  __builtin_amdgcn_global_load_lds((as1_void*)g, (as3_void*)l, 16, 0, 0);
}

__device__ __forceinline__ void waitvm(int n) {   // literal-only vmcnt
  switch (n) {
    case 0:  asm volatile("s_waitcnt vmcnt(0)"  ::: "memory"); break;
    case 4:  asm volatile("s_waitcnt vmcnt(4)"  ::: "memory"); break;
    case 6:  asm volatile("s_waitcnt vmcnt(6)"  ::: "memory"); break;
    case 8:  asm volatile("s_waitcnt vmcnt(8)"  ::: "memory"); break;
    case 12: asm volatile("s_waitcnt vmcnt(12)" ::: "memory"); break;
  }
}

// ----- rotated subtile layout (LDS kernels; verified 0 conflicts) -----
__device__ __forceinline__ int stage_kc(int lane) {            // 16B-chunk idx
  return (lane & 3) ^ ((lane >> 3) & 3);
}
__device__ __forceinline__ int frag_off(int s, int lane) {     // ushort units
  int ln = lane & 15, kg = lane >> 4;
  return s * 512 + (ln * 4 + (kg ^ ((ln >> 1) & 3))) * 8;
}

// merged f32->f16 conversion for all 5 tensors (one launch)
__global__ void k_cvt_all(const float* __restrict__ hidden, ushort_t* __restrict__ hidh,
                          const float* __restrict__ W_in,  const float* __restrict__ W_out,
                          ushort_t* __restrict__ wcat,
                          const float* __restrict__ w_ih, ushort_t* __restrict__ wihh,
                          const float* __restrict__ w_hh, ushort_t* __restrict__ whhh) {
  int blk = blockIdx.x;
  const float* src; ushort_t* dst; int base;
  if (blk < 8192)      { src = hidden; dst = hidh;           base = blk; }
  else if (blk < 8224) { src = W_in;   dst = wcat;           base = blk - 8192; }
  else if (blk < 8256) { src = W_out;  dst = wcat + 65536;   base = blk - 8224; }
  else if (blk < 8448) { src = w_ih;   dst = wihh;           base = blk - 8256; }
  else                 { src = w_hh;   dst = whhh;           base = blk - 8448; }
  int i = base * 256 + threadIdx.x;
  const float* p = src + (size_t)i * 8;
  f32x4 a = *(const f32x4*)p;
  f32x4 b = *(const f32x4*)(p + 4);
  s16x8 o;
  o[0]=(short)f2h(a[0]); o[1]=(short)f2h(a[1]); o[2]=(short)f2h(a[2]); o[3]=(short)f2h(a[3]);
  o[4]=(short)f2h(b[0]); o[5]=(short)f2h(b[1]); o[6]=(short)f2h(b[2]); o[7]=(short)f2h(b[3]);
  *(s16x8*)(dst + (size_t)i * 8) = o;
}

// K1: h_catT[b][n][j] = sum_k hid_h[b*512+j][k] * Wcat[n][k] + bcat[n]
__global__ __launch_bounds__(256, 2)
void k_gemm1(const ushort_t* __restrict__ hid, const ushort_t* __restrict__ wcat,
             const float* __restrict__ b_in, const float* __restrict__ b_out,
             ushort_t* __restrict__ hcatT) {
  __shared__ __attribute__((aligned(16))) ushort_t lA[3][8*512];
  __shared__ __attribute__((aligned(16))) ushort_t lB[3][16*512];
  const int flat = blockIdx.y * 8 + blockIdx.x;
  const int orig = (flat & 7) * 128 + (flat >> 3);
  const int bx = orig & 7, bb = orig >> 3;
  const int j0 = (bx >> 1) * 128;
  const int n0 = (bx & 1) * 256;
  const int tid = threadIdx.x;
  const int w = tid >> 6, lane = tid & 63;
  const int ln = lane & 15, kg = lane >> 4;
  const int wm = w >> 1, wn = w & 1;
  const int srow = lane >> 2, skc = stage_kc(lane);

  f32x4 acc[4][8];
  #pragma unroll
  for (int i = 0; i < 4; ++i)
    #pragma unroll
    for (int j = 0; j < 8; ++j) acc[i][j] = (f32x4){0.f,0.f,0.f,0.f};

  const size_t arow0 = (size_t)bb * 512 + j0;

  auto stage = [&](int t, int bsel) {
    int k0 = t * 32;
    #pragma unroll
    for (int it = 0; it < 2; ++it) {
      int s = it*4 + w;
      cp16(hid + (arow0 + s*16 + srow)*256 + k0 + skc*8, &lA[bsel][s*512]);
    }
    #pragma unroll
    for (int it = 0; it < 4; ++it) {
      int s = it*4 + w;
      cp16(wcat + (size_t)(n0 + s*16 + srow)*256 + k0 + skc*8, &lB[bsel][s*512]);
    }
  };
  auto compute = [&](int cur) {
    s16x8 af[4];
    #pragma unroll
    for (int mf = 0; mf < 4; ++mf)
      af[mf] = *(const s16x8*)&lA[cur][frag_off(wm*4 + mf, lane)];
    __builtin_amdgcn_s_setprio(1);
    #pragma unroll
    for (int nf = 0; nf < 8; ++nf) {
      s16x8 bf = *(const s16x8*)&lB[cur][frag_off(wn*8 + nf, lane)];
      #pragma unroll
      for (int mf = 0; mf < 4; ++mf) acc[mf][nf] = mfma16(af[mf], bf, acc[mf][nf]);
    }
    __builtin_amdgcn_s_setprio(0);
  };

  stage(0, 0); stage(1, 1);
  for (int t = 0; t < 6; ++t) {
    waitvm(6);
    __builtin_amdgcn_s_barrier();
    stage(t + 2, (t + 2) % 3);
    compute(t % 3);
  }
  waitvm(6); __builtin_amdgcn_s_barrier(); compute(6 % 3);
  waitvm(0); __builtin_amdgcn_s_barrier(); compute(7 % 3);

  #pragma unroll
  for (int nf = 0; nf < 8; ++nf) {
    int gn = n0 + wn*128 + nf*16 + ln;
    float bias = (gn < 256) ? b_in[gn] : b_out[gn - 256];
    #pragma unroll
    for (int mf = 0; mf < 4; ++mf) {
      int j = j0 + wm*64 + mf*16 + kg*4;
      u16x4 v;
      #pragma unroll
      for (int r = 0; r < 4; ++r) v[r] = f2h(acc[mf][nf][r] + bias);
      *(u16x4*)&hcatT[((size_t)(bb*512 + gn))*512 + j] = v;
    }
  }
}

// K2: inputs[b][i][h'] = sum_j A[b][i][half*512+j] * h_catT[b][h'][j] + bias(h')
__global__ __launch_bounds__(256, 2)
void k_gemm2(const float* __restrict__ A, const ushort_t* __restrict__ hcatT,
             const float* __restrict__ b_iah, const float* __restrict__ b_oah,
             ushort_t* __restrict__ inp) {
  __shared__ __attribute__((aligned(16))) ushort_t lA[2][8*512];   // reg-staged A
  __shared__ __attribute__((aligned(16))) ushort_t lB[3][16*512];  // cp16 B
  const int flat = blockIdx.y * 8 + blockIdx.x;
  const int orig = (flat & 7) * 128 + (flat >> 3);
  const int bx = orig & 7, bb = orig >> 3;
  const int i0 = (bx >> 1) * 128;
  const int half = bx & 1;
  const int n0 = half * 256;
  const int tid = threadIdx.x;
  const int w = tid >> 6, lane = tid & 63;
  const int ln = lane & 15, kg = lane >> 4;
  const int wm = w >> 1, wn = w & 1;
  const int srow = lane >> 2, skc = stage_kc(lane);

  f32x4 acc[4][8];
  #pragma unroll
  for (int i = 0; i < 4; ++i)
    #pragma unroll
    for (int j = 0; j < 8; ++j) acc[i][j] = (f32x4){0.f,0.f,0.f,0.f};

  const float* Abase = A + ((size_t)bb*512 + i0)*1024 + half*512;
  f32x4 ra[2][4];

  auto loadA = [&](int t, f32x4 (&r)[4]) {
    int k0 = t * 32;
    #pragma unroll
    for (int it = 0; it < 2; ++it) {
      int s = it*4 + w;
      const float* p = Abase + (size_t)(s*16 + srow)*1024 + k0 + skc*8;
      r[it*2]   = *(const f32x4*)p;
      r[it*2+1] = *(const f32x4*)(p + 4);
    }
  };
  auto stageB = [&](int t, int bsel) {
    int k0 = t * 32;
    #pragma unroll
    for (int it = 0; it < 4; ++it) {
      int s = it*4 + w;
      cp16(hcatT + ((size_t)(bb*512 + n0 + s*16 + srow))*512 + k0 + skc*8, &lB[bsel][s*512]);
    }
  };
  auto writeA = [&](const f32x4 (&r)[4], int bsel) {
    #pragma unroll
    for (int it = 0; it < 2; ++it) {
      int s = it*4 + w;
      s16x8 o;
      o[0]=(short)f2h(r[it*2][0]); o[1]=(short)f2h(r[it*2][1]);
      o[2]=(short)f2h(r[it*2][2]); o[3]=(short)f2h(r[it*2][3]);
      o[4]=(short)f2h(r[it*2+1][0]); o[5]=(short)f2h(r[it*2+1][1]);
      o[6]=(short)f2h(r[it*2+1][2]); o[7]=(short)f2h(r[it*2+1][3]);
      *(s16x8*)&lA[bsel][s*512 + lane*8] = o;
    }
  };
  auto compute = [&](int acur, int bcur) {
    s16x8 af[4];
    #pragma unroll
    for (int mf = 0; mf < 4; ++mf)
      af[mf] = *(const s16x8*)&lA[acur][frag_off(wm*4 + mf, lane)];
    __builtin_amdgcn_s_setprio(1);
    #pragma unroll
    for (int nf = 0; nf < 8; ++nf) {
      s16x8 bf = *(const s16x8*)&lB[bcur][frag_off(wn*8 + nf, lane)];
      #pragma unroll
      for (int mf = 0; mf < 4; ++mf) acc[mf][nf] = mfma16(af[mf], bf, acc[mf][nf]);
    }
    __builtin_amdgcn_s_setprio(0);
  };

  loadA(0, ra[0]); stageB(0, 0);
  loadA(1, ra[1]); stageB(1, 1);
  waitvm(12);
  writeA(ra[0], 0);
  asm volatile("s_waitcnt lgkmcnt(0)" ::: "memory");

  #pragma unroll
  for (int t = 0; t < 16; ++t) {
    waitvm(t < 15 ? 8 : 0);
    __builtin_amdgcn_s_barrier();
    if (t + 2 < 16) { loadA(t + 2, ra[t & 1]); stageB(t + 2, (t + 2) % 3); }
    compute(t & 1, t % 3);
    if (t + 1 < 16) {
      waitvm(t + 2 < 16 ? 12 : 4);
      writeA(ra[(t + 1) & 1], (t + 1) & 1);
      asm volatile("s_waitcnt lgkmcnt(0)" ::: "memory");
    }
  }

  #pragma unroll
  for (int nf = 0; nf < 8; ++nf) {
    int gn = n0 + wn*128 + nf*16 + ln;
    float bias = half ? b_oah[gn - 256] : b_iah[gn];
    #pragma unroll
    for (int mf = 0; mf < 4; ++mf) {
      #pragma unroll
      for (int r = 0; r < 4; ++r) {
        int i = i0 + wm*64 + mf*16 + kg*4 + r;
        inp[((size_t)(bb*512 + i))*512 + gn] = f2h(acc[mf][nf][r] + bias);
      }
    }
  }
}

// K3 v5: barrier-free, LDS-free. 1 wave per block (64 thr), tile 64M x 16h.
// MFMA fragments loaded DIRECTLY global->VGPR (L2-hot via swizzle: 16 h-blocks
// share each inp m-tile; weights ~1.1MB resident). Register software pipeline,
// fully unrolled; compiler emits counted vmcnt for plain loads. Zero sync.
__global__ __launch_bounds__(64, 3)
void k_gemm3(const ushort_t* __restrict__ inp, const ushort_t* __restrict__ hidh,
             const ushort_t* __restrict__ wih, const ushort_t* __restrict__ whh,
             const float* __restrict__ b_ih, const float* __restrict__ b_hh,
             float* __restrict__ out) {
  const int flat = blockIdx.x;                  // 16384 blocks
  const int orig = (flat & 7) * 2048 + (flat >> 3);   // XCD chunks of 2048
  const int h0 = (orig & 15) * 16;              // h fastest: 16 blocks share m-tile
  const int m0 = (orig >> 4) * 64;
  const int lane = threadIdx.x;
  const int ln = lane & 15, kg = lane >> 4;

  f32x4 aR[4], aI[4], aIN[4], aHN[4];
  #pragma unroll
  for (int m = 0; m < 4; ++m) {
    aR[m] = (f32x4){0.f,0.f,0.f,0.f}; aI[m] = (f32x4){0.f,0.f,0.f,0.f};
    aIN[m] = (f32x4){0.f,0.f,0.f,0.f}; aHN[m] = (f32x4){0.f,0.f,0.f,0.f};
  }

  // per-lane fragment bases (k advances by compile-time offsets after unroll)
  const ushort_t* pAgi = inp  + (size_t)(m0 + ln)*512 + kg*8;   // + mf*16*512 + t*32
  const ushort_t* pBgi = wih  + (size_t)(h0 + ln)*512 + kg*8;   // + g*256*512 + t*32
  const ushort_t* pAgh = hidh + (size_t)(m0 + ln)*256 + kg*8;
  const ushort_t* pBgh = whh  + (size_t)(h0 + ln)*256 + kg*8;

  auto loadfrags = [&](int t, s16x8 (&fa)[4], s16x8 (&fb)[3]) {
    if (t < 16) {
      int k0 = t * 32;
      #pragma unroll
      for (int mf = 0; mf < 4; ++mf)
        fa[mf] = *(const s16x8*)(pAgi + (size_t)mf*16*512 + k0);
      #pragma unroll
      for (int g = 0; g < 3; ++g)
        fb[g] = *(const s16x8*)(pBgi + (size_t)g*256*512 + k0);
    } else {
      int k0 = (t - 16) * 32;
      #pragma unroll
      for (int mf = 0; mf < 4; ++mf)
        fa[mf] = *(const s16x8*)(pAgh + (size_t)mf*16*256 + k0);
      #pragma unroll
      for (int g = 0; g < 3; ++g)
        fb[g] = *(const s16x8*)(pBgh + (size_t)g*256*256 + k0);
    }
  };

  s16x8 cA[4], cB[3];
  loadfrags(0, cA, cB);
  #pragma unroll
  for (int t = 0; t < 24; ++t) {
    s16x8 nA[4], nB[3];
    if (t + 1 < 24) loadfrags(t + 1, nA, nB);     // prefetch next step
    __builtin_amdgcn_s_setprio(1);
    #pragma unroll
    for (int mf = 0; mf < 4; ++mf) {
      aR[mf] = mfma16(cA[mf], cB[0], aR[mf]);
      aI[mf] = mfma16(cA[mf], cB[1], aI[mf]);
      if (t < 16) aIN[mf] = mfma16(cA[mf], cB[2], aIN[mf]);
      else        aHN[mf] = mfma16(cA[mf], cB[2], aHN[mf]);
    }
    __builtin_amdgcn_s_setprio(0);
    if (t + 1 < 24) {
      #pragma unroll
      for (int i = 0; i < 4; ++i) cA[i] = nA[i];
      #pragma unroll
      for (int i = 0; i < 3; ++i) cB[i] = nB[i];
    }
  }

  // epilogue: gates + residual (hv from fp16 hidh)
  {
    int h = h0 + ln;
    float br  = b_ih[h]       + b_hh[h];
    float bi  = b_ih[256 + h] + b_hh[256 + h];
    float bni = b_ih[512 + h];
    float bnh = b_hh[512 + h];
    #pragma unroll
    for (int mf = 0; mf < 4; ++mf) {
      #pragma unroll
      for (int r = 0; r < 4; ++r) {
        int m = m0 + mf*16 + kg*4 + r;
        float rg = 1.0f / (1.0f + __expf(-(aR[mf][r] + br)));
        float ig = 1.0f / (1.0f + __expf(-(aI[mf][r] + bi)));
        float narg = aIN[mf][r] + bni + rg * (aHN[mf][r] + bnh);
        float e2 = __expf(2.0f * narg);
        float ng = 1.0f - 2.0f / (e2 + 1.0f);
        float hv = h2f(hidh[(size_t)m*256 + h]);
        out[(size_t)m*256 + h] = hv + ig * (ng - hv);
      }
    }
  }
}

extern "C" void kernel_launch(void* const* d_in, const int* in_sizes, int n_in,
                              void* d_out, int out_size, void* d_ws, size_t ws_size,
                              hipStream_t stream) {
  const float* A      = (const float*)d_in[0];
  const float* hidden = (const float*)d_in[1];
  const float* W_in   = (const float*)d_in[3];
  const float* b_in   = (const float*)d_in[4];
  const float* W_out  = (const float*)d_in[5];
  const float* b_out  = (const float*)d_in[6];
  const float* b_iah  = (const float*)d_in[7];
  const float* b_oah  = (const float*)d_in[8];
  const float* w_ih   = (const float*)d_in[9];
  const float* b_ih   = (const float*)d_in[10];
  const float* w_hh   = (const float*)d_in[11];
  const float* b_hh   = (const float*)d_in[12];
  float* out = (float*)d_out;

  char* ws = (char*)d_ws;
  ushort_t* hidh  = (ushort_t*)(ws);                 // 32 MB
  ushort_t* wcat  = (ushort_t*)(ws + 33554432);      // 256 KB
  ushort_t* wihh  = (ushort_t*)(ws + 33816576);      // 768 KB
  ushort_t* whhh  = (ushort_t*)(ws + 34603008);      // 384 KB
  ushort_t* hcatT = (ushort_t*)(ws + 34996224);      // 64 MB
  ushort_t* inp   = (ushort_t*)(ws + 102105088);     // 64 MB  (total ~161.4 MB)

  k_cvt_all<<<8544, 256, 0, stream>>>(hidden, hidh, W_in, W_out, wcat,
                                      w_ih, wihh, w_hh, whhh);

  k_gemm1<<<dim3(8, 128), 256, 0, stream>>>(hidh, wcat, b_in, b_out, hcatT);
  k_gemm2<<<dim3(8, 128), 256, 0, stream>>>(A, hcatT, b_iah, b_oah, inp);
  k_gemm3<<<16384, 64, 0, stream>>>(inp, hidh, wihh, whhh, b_ih, b_hh, out);
}

// Round 11
// 263.875 us; speedup vs baseline: 1.7133x; 1.7133x over previous
//
#include <hip/hip_runtime.h>

#define B_ 128
#define S_ 512
#define H_ 256
#define M_ (B_*S_)

typedef __attribute__((ext_vector_type(4))) float f32x4;
typedef __attribute__((ext_vector_type(8))) short s16x8;
typedef __attribute__((ext_vector_type(4))) unsigned short u16x4;
typedef unsigned short ushort_t;

typedef __attribute__((address_space(1))) void as1_void;
typedef __attribute__((address_space(3))) void as3_void;

__device__ __forceinline__ unsigned short f2h(float f) {
  _Float16 h = (_Float16)f;              // v_cvt_f16_f32, RTNE
  return __builtin_bit_cast(unsigned short, h);
}
__device__ __forceinline__ float h2f(ushort_t u) {
  return (float)__builtin_bit_cast(_Float16, u);
}

__device__ __forceinline__ f32x4 mfma16(s16x8 a, s16x8 b, f32x4 c) {
  asm("v_mfma_f32_16x16x32_f16 %0, %1, %2, %0" : "+v"(c) : "v"(a), "v"(b));
  return c;
}

__device__ __forceinline__ void cp16(const void* g, void* l) {
  __builtin_amdgcn_global_load_lds((as1_void*)g, (as3_void*)l, 16, 0, 0);
}

__device__ __forceinline__ void waitvm(int n) {   // literal-only vmcnt
  switch (n) {
    case 0:  asm volatile("s_waitcnt vmcnt(0)"  ::: "memory"); break;
    case 4:  asm volatile("s_waitcnt vmcnt(4)"  ::: "memory"); break;
    case 5:  asm volatile("s_waitcnt vmcnt(5)"  ::: "memory"); break;
    case 6:  asm volatile("s_waitcnt vmcnt(6)"  ::: "memory"); break;
    case 8:  asm volatile("s_waitcnt vmcnt(8)"  ::: "memory"); break;
    case 12: asm volatile("s_waitcnt vmcnt(12)" ::: "memory"); break;
  }
}

// ----- rotated subtile layout (verified: 0 bank conflicts, full coalescing) -----
__device__ __forceinline__ int stage_kc(int lane) {            // 16B-chunk idx
  return (lane & 3) ^ ((lane >> 3) & 3);
}
__device__ __forceinline__ int frag_off(int s, int lane) {     // ushort units
  int ln = lane & 15, kg = lane >> 4;
  return s * 512 + (ln * 4 + (kg ^ ((ln >> 1) & 3))) * 8;
}

// merged f32->f16 conversion for all 5 tensors (one launch)
__global__ void k_cvt_all(const float* __restrict__ hidden, ushort_t* __restrict__ hidh,
                          const float* __restrict__ W_in,  const float* __restrict__ W_out,
                          ushort_t* __restrict__ wcat,
                          const float* __restrict__ w_ih, ushort_t* __restrict__ wihh,
                          const float* __restrict__ w_hh, ushort_t* __restrict__ whhh) {
  int blk = blockIdx.x;
  const float* src; ushort_t* dst; int base;
  if (blk < 8192)      { src = hidden; dst = hidh;           base = blk; }
  else if (blk < 8224) { src = W_in;   dst = wcat;           base = blk - 8192; }
  else if (blk < 8256) { src = W_out;  dst = wcat + 65536;   base = blk - 8224; }
  else if (blk < 8448) { src = w_ih;   dst = wihh;           base = blk - 8256; }
  else                 { src = w_hh;   dst = whhh;           base = blk - 8448; }
  int i = base * 256 + threadIdx.x;
  const float* p = src + (size_t)i * 8;
  f32x4 a = *(const f32x4*)p;
  f32x4 b = *(const f32x4*)(p + 4);
  s16x8 o;
  o[0]=(short)f2h(a[0]); o[1]=(short)f2h(a[1]); o[2]=(short)f2h(a[2]); o[3]=(short)f2h(a[3]);
  o[4]=(short)f2h(b[0]); o[5]=(short)f2h(b[1]); o[6]=(short)f2h(b[2]); o[7]=(short)f2h(b[3]);
  *(s16x8*)(dst + (size_t)i * 8) = o;
}

// K1: h_catT[b][n][j] = sum_k hid_h[b*512+j][k] * Wcat[n][k] + bcat[n]
__global__ __launch_bounds__(256, 2)
void k_gemm1(const ushort_t* __restrict__ hid, const ushort_t* __restrict__ wcat,
             const float* __restrict__ b_in, const float* __restrict__ b_out,
             ushort_t* __restrict__ hcatT) {
  __shared__ __attribute__((aligned(16))) ushort_t lA[3][8*512];
  __shared__ __attribute__((aligned(16))) ushort_t lB[3][16*512];
  const int flat = blockIdx.y * 8 + blockIdx.x;
  const int orig = (flat & 7) * 128 + (flat >> 3);
  const int bx = orig & 7, bb = orig >> 3;
  const int j0 = (bx >> 1) * 128;
  const int n0 = (bx & 1) * 256;
  const int tid = threadIdx.x;
  const int w = tid >> 6, lane = tid & 63;
  const int ln = lane & 15, kg = lane >> 4;
  const int wm = w >> 1, wn = w & 1;
  const int srow = lane >> 2, skc = stage_kc(lane);

  f32x4 acc[4][8];
  #pragma unroll
  for (int i = 0; i < 4; ++i)
    #pragma unroll
    for (int j = 0; j < 8; ++j) acc[i][j] = (f32x4){0.f,0.f,0.f,0.f};

  const size_t arow0 = (size_t)bb * 512 + j0;

  auto stage = [&](int t, int bsel) {
    int k0 = t * 32;
    #pragma unroll
    for (int it = 0; it < 2; ++it) {
      int s = it*4 + w;
      cp16(hid + (arow0 + s*16 + srow)*256 + k0 + skc*8, &lA[bsel][s*512]);
    }
    #pragma unroll
    for (int it = 0; it < 4; ++it) {
      int s = it*4 + w;
      cp16(wcat + (size_t)(n0 + s*16 + srow)*256 + k0 + skc*8, &lB[bsel][s*512]);
    }
  };
  auto compute = [&](int cur) {
    s16x8 af[4];
    #pragma unroll
    for (int mf = 0; mf < 4; ++mf)
      af[mf] = *(const s16x8*)&lA[cur][frag_off(wm*4 + mf, lane)];
    __builtin_amdgcn_s_setprio(1);
    #pragma unroll
    for (int nf = 0; nf < 8; ++nf) {
      s16x8 bf = *(const s16x8*)&lB[cur][frag_off(wn*8 + nf, lane)];
      #pragma unroll
      for (int mf = 0; mf < 4; ++mf) acc[mf][nf] = mfma16(af[mf], bf, acc[mf][nf]);
    }
    __builtin_amdgcn_s_setprio(0);
  };

  stage(0, 0); stage(1, 1);
  for (int t = 0; t < 6; ++t) {
    waitvm(6);
    __builtin_amdgcn_s_barrier();
    stage(t + 2, (t + 2) % 3);
    compute(t % 3);
  }
  waitvm(6); __builtin_amdgcn_s_barrier(); compute(6 % 3);
  waitvm(0); __builtin_amdgcn_s_barrier(); compute(7 % 3);

  #pragma unroll
  for (int nf = 0; nf < 8; ++nf) {
    int gn = n0 + wn*128 + nf*16 + ln;
    float bias = (gn < 256) ? b_in[gn] : b_out[gn - 256];
    #pragma unroll
    for (int mf = 0; mf < 4; ++mf) {
      int j = j0 + wm*64 + mf*16 + kg*4;
      u16x4 v;
      #pragma unroll
      for (int r = 0; r < 4; ++r) v[r] = f2h(acc[mf][nf][r] + bias);
      *(u16x4*)&hcatT[((size_t)(bb*512 + gn))*512 + j] = v;
    }
  }
}

// K2: inputs[b][i][h'] = sum_j A[b][i][half*512+j] * h_catT[b][h'][j] + bias(h')
__global__ __launch_bounds__(256, 2)
void k_gemm2(const float* __restrict__ A, const ushort_t* __restrict__ hcatT,
             const float* __restrict__ b_iah, const float* __restrict__ b_oah,
             ushort_t* __restrict__ inp) {
  __shared__ __attribute__((aligned(16))) ushort_t lA[2][8*512];   // reg-staged A
  __shared__ __attribute__((aligned(16))) ushort_t lB[3][16*512];  // cp16 B
  const int flat = blockIdx.y * 8 + blockIdx.x;
  const int orig = (flat & 7) * 128 + (flat >> 3);
  const int bx = orig & 7, bb = orig >> 3;
  const int i0 = (bx >> 1) * 128;
  const int half = bx & 1;
  const int n0 = half * 256;
  const int tid = threadIdx.x;
  const int w = tid >> 6, lane = tid & 63;
  const int ln = lane & 15, kg = lane >> 4;
  const int wm = w >> 1, wn = w & 1;
  const int srow = lane >> 2, skc = stage_kc(lane);

  f32x4 acc[4][8];
  #pragma unroll
  for (int i = 0; i < 4; ++i)
    #pragma unroll
    for (int j = 0; j < 8; ++j) acc[i][j] = (f32x4){0.f,0.f,0.f,0.f};

  const float* Abase = A + ((size_t)bb*512 + i0)*1024 + half*512;
  f32x4 ra[2][4];

  auto loadA = [&](int t, f32x4 (&r)[4]) {
    int k0 = t * 32;
    #pragma unroll
    for (int it = 0; it < 2; ++it) {
      int s = it*4 + w;
      const float* p = Abase + (size_t)(s*16 + srow)*1024 + k0 + skc*8;
      r[it*2]   = *(const f32x4*)p;
      r[it*2+1] = *(const f32x4*)(p + 4);
    }
  };
  auto stageB = [&](int t, int bsel) {
    int k0 = t * 32;
    #pragma unroll
    for (int it = 0; it < 4; ++it) {
      int s = it*4 + w;
      cp16(hcatT + ((size_t)(bb*512 + n0 + s*16 + srow))*512 + k0 + skc*8, &lB[bsel][s*512]);
    }
  };
  auto writeA = [&](const f32x4 (&r)[4], int bsel) {
    #pragma unroll
    for (int it = 0; it < 2; ++it) {
      int s = it*4 + w;
      s16x8 o;
      o[0]=(short)f2h(r[it*2][0]); o[1]=(short)f2h(r[it*2][1]);
      o[2]=(short)f2h(r[it*2][2]); o[3]=(short)f2h(r[it*2][3]);
      o[4]=(short)f2h(r[it*2+1][0]); o[5]=(short)f2h(r[it*2+1][1]);
      o[6]=(short)f2h(r[it*2+1][2]); o[7]=(short)f2h(r[it*2+1][3]);
      *(s16x8*)&lA[bsel][s*512 + lane*8] = o;
    }
  };
  auto compute = [&](int acur, int bcur) {
    s16x8 af[4];
    #pragma unroll
    for (int mf = 0; mf < 4; ++mf)
      af[mf] = *(const s16x8*)&lA[acur][frag_off(wm*4 + mf, lane)];
    __builtin_amdgcn_s_setprio(1);
    #pragma unroll
    for (int nf = 0; nf < 8; ++nf) {
      s16x8 bf = *(const s16x8*)&lB[bcur][frag_off(wn*8 + nf, lane)];
      #pragma unroll
      for (int mf = 0; mf < 4; ++mf) acc[mf][nf] = mfma16(af[mf], bf, acc[mf][nf]);
    }
    __builtin_amdgcn_s_setprio(0);
  };

  loadA(0, ra[0]); stageB(0, 0);
  loadA(1, ra[1]); stageB(1, 1);
  waitvm(12);
  writeA(ra[0], 0);
  asm volatile("s_waitcnt lgkmcnt(0)" ::: "memory");

  #pragma unroll
  for (int t = 0; t < 16; ++t) {
    waitvm(t < 15 ? 8 : 0);
    __builtin_amdgcn_s_barrier();
    if (t + 2 < 16) { loadA(t + 2, ra[t & 1]); stageB(t + 2, (t + 2) % 3); }
    compute(t & 1, t % 3);
    if (t + 1 < 16) {
      waitvm(t + 2 < 16 ? 12 : 4);
      writeA(ra[(t + 1) & 1], (t + 1) & 1);
      asm volatile("s_waitcnt lgkmcnt(0)" ::: "memory");
    }
  }

  #pragma unroll
  for (int nf = 0; nf < 8; ++nf) {
    int gn = n0 + wn*128 + nf*16 + ln;
    float bias = half ? b_oah[gn - 256] : b_iah[gn];
    #pragma unroll
    for (int mf = 0; mf < 4; ++mf) {
      #pragma unroll
      for (int r = 0; r < 4; ++r) {
        int i = i0 + wm*64 + mf*16 + kg*4 + r;
        inp[((size_t)(bb*512 + i))*512 + gn] = f2h(acc[mf][nf][r] + bias);
      }
    }
  }
}

// K3: fused gi (K=512) + gh (K=256) + GRU gates + residual -> out fp32
// REVERT to round-6 structure (best known: 283us total): wave 64M x 32h,
// 3-buf depth-2, uniform 5 cp16/wave -> gate vmcnt(5) exact, XCD swizzle,
// setprio, grid (4,512), 2 blocks/CU. Only delta vs r6: epilogue residual
// read from fp16 hidh (saves 64MB f32 HBM stream).
__global__ __launch_bounds__(256, 2)
void k_gemm3(const ushort_t* __restrict__ inp, const ushort_t* __restrict__ hidh,
             const ushort_t* __restrict__ wih, const ushort_t* __restrict__ whh,
             const float* __restrict__ b_ih, const float* __restrict__ b_hh,
             float* __restrict__ out) {
  __shared__ __attribute__((aligned(16))) ushort_t lIn[3][8*512];
  __shared__ __attribute__((aligned(16))) ushort_t lW[3][12*512];
  // swizzle: nwg = 4*512 = 2048; 4 consecutive origs share inp m-tile -> same XCD L2
  const int flat = blockIdx.y * 4 + blockIdx.x;
  const int orig = (flat & 7) * 256 + (flat >> 3);
  const int h0 = (orig & 3) * 64;
  const int m0 = (orig >> 2) * 128;
  const int tid = threadIdx.x;
  const int w = tid >> 6, lane = tid & 63;
  const int ln = lane & 15, kg = lane >> 4;
  const int wm2 = w >> 1, wh = w & 1;          // wave: 64M x 32h
  const int srow = lane >> 2, skc = stage_kc(lane);

  f32x4 aR[4][2], aI[4][2], aIN[4][2], aHN[4][2];
  #pragma unroll
  for (int m = 0; m < 4; ++m)
    #pragma unroll
    for (int n = 0; n < 2; ++n) {
      aR[m][n] = (f32x4){0.f,0.f,0.f,0.f}; aI[m][n] = (f32x4){0.f,0.f,0.f,0.f};
      aIN[m][n] = (f32x4){0.f,0.f,0.f,0.f}; aHN[m][n] = (f32x4){0.f,0.f,0.f,0.f};
    }

  // uniform 5 cp16 per wave per stage(): 2 lIn + 3 lW
  auto stage = [&](int gs, int bsel) {
    if (gs < 16) {
      int k0 = gs * 32;
      #pragma unroll
      for (int it = 0; it < 2; ++it) {
        int s = it*4 + w;
        cp16(inp + (size_t)(m0 + s*16 + srow)*512 + k0 + skc*8, &lIn[bsel][s*512]);
      }
      #pragma unroll
      for (int it = 0; it < 3; ++it) {
        int s = it*4 + w;
        int row = s*16 + srow, g = row >> 6, r = row & 63;
        cp16(wih + (size_t)(g*256 + h0 + r)*512 + k0 + skc*8, &lW[bsel][s*512]);
      }
    } else {
      int k0 = (gs - 16) * 32;
      #pragma unroll
      for (int it = 0; it < 2; ++it) {
        int s = it*4 + w;
        cp16(hidh + (size_t)(m0 + s*16 + srow)*256 + k0 + skc*8, &lIn[bsel][s*512]);
      }
      #pragma unroll
      for (int it = 0; it < 3; ++it) {
        int s = it*4 + w;
        int row = s*16 + srow, g = row >> 6, r = row & 63;
        cp16(whh + (size_t)(g*256 + h0 + r)*256 + k0 + skc*8, &lW[bsel][s*512]);
      }
    }
  };

  auto compute = [&](int cur, f32x4 (&aN)[4][2]) {
    s16x8 af[4];
    #pragma unroll
    for (int mf = 0; mf < 4; ++mf)
      af[mf] = *(const s16x8*)&lIn[cur][frag_off(wm2*4 + mf, lane)];
    __builtin_amdgcn_s_setprio(1);
    #pragma unroll
    for (int g = 0; g < 3; ++g) {
      #pragma unroll
      for (int nf = 0; nf < 2; ++nf) {
        s16x8 bf = *(const s16x8*)&lW[cur][frag_off(g*4 + wh*2 + nf, lane)];
        #pragma unroll
        for (int mf = 0; mf < 4; ++mf) {
          f32x4& a = (g == 0 ? aR[mf][nf] : g == 1 ? aI[mf][nf] : aN[mf][nf]);
          a = mfma16(af[mf], bf, a);
        }
      }
    }
    __builtin_amdgcn_s_setprio(0);
  };

  stage(0, 0);
  stage(1, 1);
  for (int t = 0; t < 16; ++t) {          // phase 1: gi, n-gate -> aIN
    waitvm(5);
    __builtin_amdgcn_s_barrier();
    stage(t + 2, (t + 2) % 3);
    compute(t % 3, aIN);
  }
  for (int t = 16; t < 22; ++t) {         // phase 2: gh, n-gate -> aHN
    waitvm(5);
    __builtin_amdgcn_s_barrier();
    stage(t + 2, (t + 2) % 3);
    compute(t % 3, aHN);
  }
  waitvm(5); __builtin_amdgcn_s_barrier(); compute(22 % 3, aHN);
  waitvm(0); __builtin_amdgcn_s_barrier(); compute(23 % 3, aHN);

  // epilogue: gates + residual (hv from fp16 hidh)
  #pragma unroll
  for (int nf = 0; nf < 2; ++nf) {
    int h = h0 + wh*32 + nf*16 + ln;
    float br  = b_ih[h]       + b_hh[h];
    float bi  = b_ih[256 + h] + b_hh[256 + h];
    float bni = b_ih[512 + h];
    float bnh = b_hh[512 + h];
    #pragma unroll
    for (int mf = 0; mf < 4; ++mf) {
      #pragma unroll
      for (int r = 0; r < 4; ++r) {
        int m = m0 + wm2*64 + mf*16 + kg*4 + r;
        float rg = 1.0f / (1.0f + __expf(-(aR[mf][nf][r] + br)));
        float ig = 1.0f / (1.0f + __expf(-(aI[mf][nf][r] + bi)));
        float narg = aIN[mf][nf][r] + bni + rg * (aHN[mf][nf][r] + bnh);
        float e2 = __expf(2.0f * narg);
        float ng = 1.0f - 2.0f / (e2 + 1.0f);
        float hv = h2f(hidh[(size_t)m*256 + h]);
        out[(size_t)m*256 + h] = hv + ig * (ng - hv);
      }
    }
  }
}

extern "C" void kernel_launch(void* const* d_in, const int* in_sizes, int n_in,
                              void* d_out, int out_size, void* d_ws, size_t ws_size,
                              hipStream_t stream) {
  const float* A      = (const float*)d_in[0];
  const float* hidden = (const float*)d_in[1];
  const float* W_in   = (const float*)d_in[3];
  const float* b_in   = (const float*)d_in[4];
  const float* W_out  = (const float*)d_in[5];
  const float* b_out  = (const float*)d_in[6];
  const float* b_iah  = (const float*)d_in[7];
  const float* b_oah  = (const float*)d_in[8];
  const float* w_ih   = (const float*)d_in[9];
  const float* b_ih   = (const float*)d_in[10];
  const float* w_hh   = (const float*)d_in[11];
  const float* b_hh   = (const float*)d_in[12];
  float* out = (float*)d_out;

  char* ws = (char*)d_ws;
  ushort_t* hidh  = (ushort_t*)(ws);                 // 32 MB
  ushort_t* wcat  = (ushort_t*)(ws + 33554432);      // 256 KB
  ushort_t* wihh  = (ushort_t*)(ws + 33816576);      // 768 KB
  ushort_t* whhh  = (ushort_t*)(ws + 34603008);      // 384 KB
  ushort_t* hcatT = (ushort_t*)(ws + 34996224);      // 64 MB
  ushort_t* inp   = (ushort_t*)(ws + 102105088);     // 64 MB  (total ~161.4 MB)

  k_cvt_all<<<8544, 256, 0, stream>>>(hidden, hidh, W_in, W_out, wcat,
                                      w_ih, wihh, w_hh, whhh);

  k_gemm1<<<dim3(8, 128), 256, 0, stream>>>(hidh, wcat, b_in, b_out, hcatT);
  k_gemm2<<<dim3(8, 128), 256, 0, stream>>>(A, hcatT, b_iah, b_oah, inp);
  k_gemm3<<<dim3(4, 512), 256, 0, stream>>>(inp, hidh, wihh, whhh, b_ih, b_hh, out);
}